// Round 1
// baseline (128.053 us; speedup 1.0000x reference)
//
#include <hip/hip_runtime.h>

#define NB 32
#define NT 512
#define ND 384
#define NC (ND / 4)          // 96 float4 per frame
#define NFRAMES 2048         // T * MAX_DUR

// Kernel 1: one block per batch row. Scan durations, apply all-zero fallback,
// scatter frame -> source-index map into idx (-1 = padded frame).
__global__ __launch_bounds__(NT) void lr_index_kernel(const int* __restrict__ ds,
                                                      int* __restrict__ idx) {
    __shared__ int cum[NT];
    const int b = blockIdx.x;
    const int t = threadIdx.x;

    int d = ds[b * NT + t];
    cum[t] = d;
    __syncthreads();

    // Hillis-Steele inclusive scan over 512 elements (9 steps)
    #pragma unroll
    for (int off = 1; off < NT; off <<= 1) {
        int v = (t >= off) ? cum[t - off] : 0;
        __syncthreads();
        cum[t] += v;
        __syncthreads();
    }

    const int total = cum[NT - 1];   // stable: last scan step ended with a barrier
    if (total == 0) {                // all-zero row -> every duration = 1
        d = 1;
        cum[t] = t + 1;              // own element only, no cross-thread read
    }

    // init this row's idx map to -1 (coalesced, 4 entries/thread)
    int* idx_row = idx + b * NFRAMES;
    #pragma unroll
    for (int k = 0; k < NFRAMES / NT; ++k)
        idx_row[t + k * NT] = -1;
    __syncthreads();

    // scatter: frames [end-d, end) come from source position t (disjoint ranges)
    const int end = cum[t];
    for (int p = end - d; p < end; ++p)
        idx_row[p] = t;
}

// Kernel 2: vectorized gather. One float4 per thread-iteration.
__global__ __launch_bounds__(256) void lr_gather_kernel(const float4* __restrict__ xs,
                                                        const int* __restrict__ idx,
                                                        float4* __restrict__ out) {
    const int n = NB * NFRAMES * NC;               // 6,291,456
    const int stride = gridDim.x * blockDim.x;
    for (int i = blockIdx.x * blockDim.x + threadIdx.x; i < n; i += stride) {
        const int frame = i / NC;                  // magic-mul div by 96
        const int c = i - frame * NC;
        const int b = frame >> 11;                 // NFRAMES = 2048
        const int j = idx[frame];
        float4 v;
        if (j >= 0) {
            v = xs[(b * NT + j) * NC + c];
        } else {
            v = make_float4(0.f, 0.f, 0.f, 0.f);
        }
        out[i] = v;
    }
}

extern "C" void kernel_launch(void* const* d_in, const int* in_sizes, int n_in,
                              void* d_out, int out_size, void* d_ws, size_t ws_size,
                              hipStream_t stream) {
    const float* xs = (const float*)d_in[0];
    const int*   ds = (const int*)d_in[1];
    float* out = (float*)d_out;
    int* idx = (int*)d_ws;                         // NB*NFRAMES ints = 256 KB

    lr_index_kernel<<<NB, NT, 0, stream>>>(ds, idx);

    const int n = NB * NFRAMES * NC;
    const int block = 256;
    int grid = 2048;                               // grid-stride, ~12 iters/thread
    (void)n; (void)in_sizes; (void)n_in; (void)out_size; (void)ws_size;
    lr_gather_kernel<<<grid, block, 0, stream>>>((const float4*)xs, idx, (float4*)out);
}